// Round 1
// baseline (2671.114 us; speedup 1.0000x reference)
//
#include <hip/hip_runtime.h>
#include <hip/hip_bf16.h>

#define H_ 8
#define NTOT 8192
#define LG 1024
#define BN 8
#define HD 16
#define DSTATE 64
#define EPG 16384
#define MSZ (1024*1024)

typedef __hip_bfloat16 bf16;
typedef unsigned short ushort_t;
typedef _Float16 f16;
typedef __attribute__((ext_vector_type(8))) _Float16 half8;
typedef __attribute__((ext_vector_type(4))) _Float16 half4;
typedef __attribute__((ext_vector_type(4))) float f4v;

__device__ __forceinline__ float b2f(bf16 v){ return __bfloat162float(v); }
// stable softplus matching jax.nn.softplus = log1p(exp(z))
__device__ __forceinline__ float sp_(float z){
  return fmaxf(z, 0.f) + log1pf(expf(-fabsf(z)));
}
// dtype-flagged scalar load (uniform branch)
__device__ __forceinline__ float ldv(const void* p, size_t i, int f32){
  float v;
  if (f32) v = ((const float*)p)[i];
  else     v = b2f(((const bf16*)p)[i]);
  return v;
}
// async global->LDS, 16 bytes per lane
__device__ __forceinline__ void gl2lds16(const void* g, void* l){
  __builtin_amdgcn_global_load_lds((const __attribute__((address_space(1))) unsigned int*)g,
                                   (__attribute__((address_space(3))) unsigned int*)l,
                                   16, 0, 0);
}

// raw workgroup barrier with compiler-level memory fences on both sides
// (raw s_barrier does NOT get an automatic vmcnt(0) drain -> prefetch stays in flight)
#define BARC() do { asm volatile("" ::: "memory"); __builtin_amdgcn_s_barrier(); asm volatile("" ::: "memory"); } while(0)

// -------- dtype sniffer: bf16 N(0,1) data never has exponent>=140; f32-as-bf16 does.
__global__ void k_sniff(const void* __restrict__ dt, int* __restrict__ flag){
  const ushort_t* p = (const ushort_t*)dt;
  int tid = threadIdx.x;
  int bad = 0;
  for (int i = tid; i < 512; i += 256){
    int e = (p[i] >> 7) & 0xFF;
    if (e >= 140) bad = 1;
  }
  unsigned long long m = __ballot(bad != 0);
  __shared__ int anybad[4];
  if ((tid & 63) == 0) anybad[tid >> 6] = (m != 0ull) ? 1 : 0;
  __syncthreads();
  if (tid == 0) *flag = (anybad[0] | anybad[1] | anybad[2] | anybad[3]);
}

// -------- per-node coefficients. a0/a1 stored [n][h] (coalesced for k_scatter);
// dum/sdt stay [h][n] (coalesced for k_norm2/k_final2).
__global__ void k_nodecoef(const void* __restrict__ dt, const void* __restrict__ dtb,
                           const int* __restrict__ flag,
                           float* __restrict__ a0, float* __restrict__ a1,
                           float* __restrict__ dum, float* __restrict__ sdt){
  int idx = blockIdx.x*256 + threadIdx.x;
  if (idx >= H_*NTOT) return;
  int f32 = *flag;
  int h = idx / NTOT, n = idx - h*NTOT;
  float bias = ldv(dtb, h, f32);
  size_t base = (size_t)n*(4*H_) + h*4;
  float d0, d1, d2, d3;
  if (f32){
    const float* row = (const float*)dt + base;
    d0 = row[0]; d1 = row[1]; d2 = row[2]; d3 = row[3];
  } else {
    const bf16* row = (const bf16*)dt + base;
    d0 = b2f(row[0]); d1 = b2f(row[1]); d2 = b2f(row[2]); d3 = b2f(row[3]);
  }
  a0[(size_t)n*H_ + h] = -sp_(d0 + bias);
  a1[(size_t)n*H_ + h] = -sp_(d1 + bias);
  dum[idx] = expf(-sp_(d2 + bias));
  sdt[idx] = d3;
}

// -------- zero the per-bh fp32 scatter buffers (aliased at f16 matrix slots 2,3)
// plus the per-bh nrm row (x-block 1024).
__global__ __launch_bounds__(256) void k_zero(char* base, size_t regB, float* __restrict__ nrm){
  int bh = blockIdx.y;
  if (blockIdx.x < 1024){
    float* Mf = (float*)(base + (size_t)bh*regB) + MSZ;
    int i = blockIdx.x*1024 + threadIdx.x*4;
    *(float4*)(Mf + i) = make_float4(0.f,0.f,0.f,0.f);
  } else {
    int j = threadIdx.x*4;
    *(float4*)(nrm + (size_t)bh*LG + j) = make_float4(0.f,0.f,0.f,0.f);
  }
}

// -------- scatter edges into fp32 M = A^T (M[dl][sl] += attr), plus row-sum of A over sl
__global__ void k_scatter(const int* __restrict__ ei, const float* __restrict__ a0,
                          const float* __restrict__ a1, char* base, size_t regB,
                          float* __restrict__ nrm,
                          int b0, int h0, int lgHB, int GBp, int nthreads, int Etot){
  int t = blockIdx.x*256 + threadIdx.x;
  if (t >= nthreads) return;
  int HB = 1 << lgHB;
  int hl = t & (HB-1);
  int el = t >> lgHB;
  int e = b0*EPG + el;
  int src = ei[e], dst = ei[Etot + e];
  int g = src >> 10;
  if ((unsigned)(g - b0) >= (unsigned)GBp) return;
  int sl = src & 1023, dl = dst & 1023;
  int h = h0 + hl;
  float attr = expf(0.5f*(a0[(size_t)src*H_ + h] + a1[(size_t)dst*H_ + h]));
  int bhl = (g - b0)*HB + hl;
  float* Mf = (float*)(base + (size_t)bhl*regB) + MSZ;
  atomicAdd(&Mf[(size_t)dl*LG + sl], attr);
  atomicAdd(&nrm[bhl*LG + sl], attr);
}

// -------- fused normalize + transpose (32x32 tiles): from fp32 M write
// f16 L0 (slot 0), L0^T (slot 1), O0 = I+M (slot 4) in one pass.
__global__ __launch_bounds__(256) void k_norm2(char* base, size_t regB,
                            const float* __restrict__ nrm, const float* __restrict__ dum,
                            int b0, int h0, int HB){
  __shared__ ushort_t tb[32][33];
  int bh = blockIdx.z;
  int g = b0 + bh / HB, h = h0 + bh % HB;
  const float* Mf = (const float*)(base + (size_t)bh*regB) + MSZ;
  f16* L0  = (f16*)(base + (size_t)bh*regB);
  f16* L0T = L0 + MSZ;
  f16* O0  = L0 + (size_t)4*MSZ;
  int x0 = blockIdx.x*32, y0 = blockIdx.y*32;   // x: sl, y: dl
  int tx = threadIdx.x & 31, ty = threadIdx.x >> 5;  // 32 x 8
  int sl = x0 + tx;
  float denom = nrm[(size_t)bh*LG + sl] + dum[(size_t)h*NTOT + g*LG + sl] + 0.1f;
  float rden = 1.f / denom;
  #pragma unroll
  for (int i = 0; i < 32; i += 8){
    int dl = y0 + ty + i;
    float v = Mf[(size_t)dl*LG + sl] * rden;
    f16 hv = (f16)v;
    L0[(size_t)dl*LG + sl] = hv;
    O0[(size_t)dl*LG + sl] = (f16)(v + (dl == sl ? 1.f : 0.f));
    union { f16 h; ushort_t u; } cv; cv.h = hv;
    tb[tx][ty + i] = cv.u;                 // [sl-local][dl-local]
  }
  __syncthreads();
  #pragma unroll
  for (int i = 0; i < 32; i += 8){
    union { f16 h; ushort_t u; } cv; cv.u = tb[ty + i][tx];
    L0T[(size_t)(x0 + ty + i)*LG + y0 + tx] = cv.h;   // L0T[sl][dl]
  }
}

// -------- G[b][l][t] = sum_d C[b,l,d]*B[b,t,d]  -> stored f16
__global__ __launch_bounds__(256) void k_G(const void* __restrict__ Bm, const void* __restrict__ Cm,
                                           const int* __restrict__ flag,
                                           f16* __restrict__ G, int b0){
  int gl = blockIdx.z;
  int g = b0 + gl;
  int l0 = blockIdx.y*16, t0 = blockIdx.x*16;
  __shared__ float Cs[16][DSTATE+1];
  __shared__ float Bs[16][DSTATE+1];
  int tid = threadIdx.x;
  int f32 = *flag;
  if (f32){
    const float* Cf = (const float*)Cm;
    const float* Bf = (const float*)Bm;
    for (int i = tid; i < 16*DSTATE; i += 256){
      int r = i >> 6, d = i & 63;
      Cs[r][d] = Cf[(size_t)(g*LG + l0 + r)*DSTATE + d];
      Bs[r][d] = Bf[(size_t)(g*LG + t0 + r)*DSTATE + d];
    }
  } else {
    const bf16* Cb = (const bf16*)Cm;
    const bf16* Bb = (const bf16*)Bm;
    for (int i = tid; i < 16*DSTATE; i += 256){
      int r = i >> 6, d = i & 63;
      Cs[r][d] = b2f(Cb[(size_t)(g*LG + l0 + r)*DSTATE + d]);
      Bs[r][d] = b2f(Bb[(size_t)(g*LG + t0 + r)*DSTATE + d]);
    }
  }
  __syncthreads();
  int r = tid >> 4, c = tid & 15;
  float acc = 0.f;
  #pragma unroll
  for (int d = 0; d < DSTATE; ++d) acc = fmaf(Cs[r][d], Bs[c][d], acc);
  G[(size_t)gl*MSZ + (size_t)(l0+r)*LG + t0 + c] = (f16)acc;
}

// -------- r13: 256x256-tile 8-phase fused GEMM with counted vmcnt (m201-style port).
// Replaces the 128x128/BK=32 structure (28% MfmaUtil, barrier-drain bound).
// 512 thr = 8 waves (2M x 4N), per-wave output 128x64 -> acc[8][4] f32x4.
// LDS = ring of 8 half-slots x 16KB = 128KB (dynamic). Half h: K-tile h>>2,
// kind j=h&3 in {B0,B1,A0,A1} (rows (j&1)*128..+128, BK=64) -> slot h%8.
// Issue half h at phase h-6 (2 x gl2lds16 / thread, linear LDS dest,
// PRE-SWIZZLED global source: chunk c = (t&7) ^ (row&7)); read side applies
// the same XOR -> conflict-free ds_read_b128. Race-freedom: B slots retire
// (last ds_read) at phase 1 of their tile, A slots at phase 3; issue at
// phase P overwrites the slot of half P-2 whose last read is >=1 barrier
// earlier. Boundary wait: s_waitcnt vmcnt(4) once per K-tile (vmcnt(0) only
// before the last tile) - never a full drain mid-loop. Phases per K-tile:
// P0 af(mt0-3,ks0)+bf[0], P1 af(mt4-7,ks0)+bf[1], P2 af(mt0-3,ks1),
// P3 af(mt4-7,ks1); 16 MFMA each wrapped in s_setprio(1/0); 2 raw
// s_barrier per phase (no compiler vmcnt(0) drain).
__global__ __launch_bounds__(512, 2) void k_gemm_fused(char* base, size_t regB,
    int nS, int iAs, int iBTs, int iCs, int iCTs,
    int nU, int iAu, int iBTu, int iCu){
  extern __shared__ char lds[];
  int T = nS + nU;
  int s = blockIdx.z;
  if (s >= T) return;
  int isS = (s < nS) ? 1 : 0;
  int bh  = isS ? s : (s - nS);
  int iA  = isS ? iAs : iAu;
  int iBT = isS ? iBTs : iBTu;
  int iC  = isS ? iCs : iCu;
  int iCT = isS ? iCTs : -1;
  int addA = 1 - isS;
  char* reg = base + (size_t)bh*regB;
  const f16* Ab = (const f16*)reg + (size_t)iA*MSZ;
  const f16* Bb = (const f16*)reg + (size_t)iBT*MSZ;
  f16* Cb = (f16*)reg + (size_t)iC*MSZ;
  int i0 = blockIdx.y*256, j0 = blockIdx.x*256;
  int tid = threadIdx.x;
  int lane = tid & 63, wv = tid >> 6;          // 8 waves
  int wm = wv >> 2, wn = wv & 3;               // 2 x 4 wave grid
  int m16 = lane & 15, q = lane >> 4;
  int rswz  = m16*128 + ((q ^ (m16 & 7)) << 4);  // ks=0 swizzled lane offset
  int rswz1 = rswz ^ 64;                          // ks=1 (chunk +4 under XOR)
  int bcol = (wn & 1) << 13;                   // col-base byte offset in B half-slot
  // staging constants: thread t covers row sr (within 64-row group), chunk sc
  int sr = tid >> 3;
  int sc = (tid & 7) ^ (sr & 7);               // pre-swizzled source chunk

  auto ISSUE = [&](int h){                     // stage half-tile h (uniform h)
    if (h >= 64) return;
    int j = h & 3;
    const f16* M = (j < 2) ? Bb : Ab;
    int rb = ((j < 2) ? j0 : i0) + ((j & 1) << 7);
    const f16* src = M + (size_t)(rb + sr)*LG + ((h >> 2) << 6) + sc*8;
    char* dst = lds + ((h & 7) << 14) + tid*16;
    gl2lds16(src, dst);                        // rows rb+0..63
    gl2lds16(src + (size_t)64*LG, dst + 8192); // rows rb+64..127
  };

  // prologue: tile0 (h0-3) + tile1 B halves (h4,5); wait tile0 (4 newest ok)
  ISSUE(0); ISSUE(1); ISSUE(2); ISSUE(3); ISSUE(4); ISSUE(5);
  f4v acc[8][4] = {};
  half8 af[4], bfr[2][4];
  asm volatile("s_waitcnt vmcnt(4)" ::: "memory");
  BARC();

  for (int kt = 0; kt < 16; ++kt){
    int sb = (kt & 1) << 2;
    const char* Asl = lds + ((sb + 2 + wm) << 14);
    const char* Bsl = lds + ((sb + (wn >> 1)) << 14) + bcol;
    int h0 = kt*4 + 6;
    // ---- phase 0: af(mt0-3, ks0) + bf[0]; issue h0 (next-tile A0)
    #pragma unroll
    for (int t = 0; t < 4; ++t) af[t] = *(const half8*)(Asl + t*2048 + rswz);
    #pragma unroll
    for (int t = 0; t < 4; ++t) bfr[0][t] = *(const half8*)(Bsl + t*2048 + rswz);
    ISSUE(h0);
    BARC();
    asm volatile("s_waitcnt lgkmcnt(0)" ::: "memory");
    __builtin_amdgcn_s_setprio(1);
    #pragma unroll
    for (int mt = 0; mt < 4; ++mt)
      #pragma unroll
      for (int nt = 0; nt < 4; ++nt)
        acc[mt][nt] = __builtin_amdgcn_mfma_f32_16x16x32_f16(af[mt], bfr[0][nt], acc[mt][nt], 0, 0, 0);
    __builtin_amdgcn_s_setprio(0);
    BARC();
    // ---- phase 1: af(mt4-7, ks0) + bf[1]; issue h0+1 (next-tile A1)
    #pragma unroll
    for (int t = 0; t < 4; ++t) af[t] = *(const half8*)(Asl + 8192 + t*2048 + rswz);
    #pragma unroll
    for (int t = 0; t < 4; ++t) bfr[1][t] = *(const half8*)(Bsl + t*2048 + rswz1);
    ISSUE(h0 + 1);
    BARC();
    asm volatile("s_waitcnt lgkmcnt(0)" ::: "memory");
    __builtin_amdgcn_s_setprio(1);
    #pragma unroll
    for (int mt = 0; mt < 4; ++mt)
      #pragma unroll
      for (int nt = 0; nt < 4; ++nt)
        acc[4 + mt][nt] = __builtin_amdgcn_mfma_f32_16x16x32_f16(af[mt], bfr[0][nt], acc[4 + mt][nt], 0, 0, 0);
    __builtin_amdgcn_s_setprio(0);
    BARC();
    // ---- phase 2: af(mt0-3, ks1); issue h0+2 (tile+2 B0, overwrites retired B0)
    #pragma unroll
    for (int t = 0; t < 4; ++t) af[t] = *(const half8*)(Asl + t*2048 + rswz1);
    ISSUE(h0 + 2);
    BARC();
    asm volatile("s_waitcnt lgkmcnt(0)" ::: "memory");
    __builtin_amdgcn_s_setprio(1);
    #pragma unroll
    for (int mt = 0; mt < 4; ++mt)
      #pragma unroll
      for (int nt = 0; nt < 4; ++nt)
        acc[mt][nt] = __builtin_amdgcn_mfma_f32_16x16x32_f16(af[mt], bfr[1][nt], acc[mt][nt], 0, 0, 0);
    __builtin_amdgcn_s_setprio(0);
    BARC();
    // ---- phase 3: af(mt4-7, ks1); issue h0+3 (tile+2 B1); boundary wait
    #pragma unroll
    for (int t = 0; t < 4; ++t) af[t] = *(const half8*)(Asl + 8192 + t*2048 + rswz1);
    ISSUE(h0 + 3);
    BARC();
    asm volatile("s_waitcnt lgkmcnt(0)" ::: "memory");
    __builtin_amdgcn_s_setprio(1);
    #pragma unroll
    for (int mt = 0; mt < 4; ++mt)
      #pragma unroll
      for (int nt = 0; nt < 4; ++nt)
        acc[4 + mt][nt] = __builtin_amdgcn_mfma_f32_16x16x32_f16(af[mt], bfr[1][nt], acc[4 + mt][nt], 0, 0, 0);
    __builtin_amdgcn_s_setprio(0);
    if (kt < 14)       asm volatile("s_waitcnt vmcnt(4)" ::: "memory");
    else if (kt == 14) asm volatile("s_waitcnt vmcnt(0)" ::: "memory");
    BARC();
  }

  f16* CT = (f16*)reg + (size_t)((iCT < 0) ? iC : iCT)*MSZ;
  // epilogue: D lane mapping col=lane&15, row=(lane>>4)*4+r (same as r10)
  #pragma unroll
  for (int mt = 0; mt < 8; ++mt){
    #pragma unroll
    for (int nt = 0; nt < 4; ++nt){
      int gr0 = i0 + wm*128 + mt*16 + q*4;
      int gc  = j0 + wn*64 + nt*16 + m16;
      half4 tv;
      #pragma unroll
      for (int r = 0; r < 4; ++r){
        float v = acc[mt][nt][r];
        if (addA) v += (float)Ab[(size_t)(gr0 + r)*LG + gc];
        f16 hv = (f16)v;
        tv[r] = hv;
        Cb[(size_t)(gr0 + r)*LG + gc] = hv;
      }
      if (iCT >= 0)
        *(half4*)&CT[(size_t)gc*LG + gr0] = tv;
    }
  }
}

// -------- final: y[l,d] = sum_t O[l,t]*s[t]*G[l,t]*x[t,d] + x[l,d]*D[h]
// block: 16 l-rows x one bh; t-chunked coef tile in LDS; thread = (l, d)
// (r10's proven single-pass version — the r12 two-stage split was neutral-to-worse)
__global__ __launch_bounds__(256) void k_final2(char* base, size_t regB, int iO,
    const f16* __restrict__ Gh, const float* __restrict__ sdt,
    const void* __restrict__ x, const void* __restrict__ Dv,
    const int* __restrict__ flag, void* __restrict__ out,
    int b0, int h0, int HB){
  __shared__ float coef[16][257];
  int bh = blockIdx.y;
  int gl = bh / HB, g = b0 + gl, h = h0 + bh % HB;
  int L0r = blockIdx.x*16;
  int tid = threadIdx.x;
  int lr = tid >> 4, ts = tid & 15;   // phase1: (row lr, t-seg ts); phase2: (row lr, d=ts)
  int f32 = *flag;
  const f16* Orow = (const f16*)(base + (size_t)bh*regB) + (size_t)iO*MSZ + (size_t)(L0r+lr)*LG;
  const f16* Grow = Gh + (size_t)gl*MSZ + (size_t)(L0r+lr)*LG;
  const float* srow = sdt + (size_t)h*NTOT + g*LG;
  float acc = 0.f;
  for (int tc = 0; tc < LG; tc += 256){
    int tb = tc + ts*16;
    __syncthreads();
    half8 o0 = *(const half8*)&Orow[tb];
    half8 o1 = *(const half8*)&Orow[tb + 8];
    half8 g0 = *(const half8*)&Grow[tb];
    half8 g1 = *(const half8*)&Grow[tb + 8];
    #pragma unroll
    for (int j = 0; j < 8; ++j){
      coef[lr][ts*16 + j]     = (float)o0[j] * (float)g0[j] * srow[tb + j];
      coef[lr][ts*16 + 8 + j] = (float)o1[j] * (float)g1[j] * srow[tb + 8 + j];
    }
    __syncthreads();
    if (f32){
      const float* xf = (const float*)x + (size_t)(g*LG + tc)*128 + h*HD + ts;
      for (int t = 0; t < 256; ++t)
        acc = fmaf(coef[lr][t], xf[(size_t)t*128], acc);
    } else {
      const bf16* xb = (const bf16*)x + (size_t)(g*LG + tc)*128 + h*HD + ts;
      for (int t = 0; t < 256; ++t)
        acc = fmaf(coef[lr][t], b2f(xb[(size_t)t*128]), acc);
    }
  }
  int l = L0r + lr, d = ts;
  float xs = ldv(x, (size_t)(g*LG + l)*128 + h*HD + d, f32);
  float dv = ldv(Dv, h, f32);
  float v = acc + xs*dv;
  size_t off = (size_t)(g*LG + l)*128 + d*H_ + h;
  if (f32) ((float*)out)[off] = v;
  else     ((bf16*)out)[off] = __float2bfloat16(v);
}

extern "C" void kernel_launch(void* const* d_in, const int* in_sizes, int n_in,
                              void* d_out, int out_size, void* d_ws, size_t ws_size,
                              hipStream_t stream){
  const void* x   = d_in[0];
  const void* Bm  = d_in[1];
  const void* Cm  = d_in[2];
  const void* dt  = d_in[3];
  const void* dtb = d_in[4];
  const void* Dv  = d_in[5];
  const int*  ei  = (const int*)d_in[6];
  int Etot = in_sizes[6] / 2;  // 131072

  // allow 128 KiB dynamic LDS for the GEMM (once per process; host-side, capture-safe)
  static int attrDone = 0;
  if (!attrDone){
    hipFuncSetAttribute(reinterpret_cast<const void*>(k_gemm_fused),
                        hipFuncAttributeMaxDynamicSharedMemorySize, 131072);
    attrDone = 1;
  }

  // per-(b,h) chain region: 6 f16 matrices (12 MB):
  //   slots 0-3: L/LT ping-pong pairs, 4,5: O ping/pong
  //   fp32 scatter buffer (4 MB) aliases slots 2+3 (dead before first GEMM writes them)
  const size_t REG = (size_t)6*MSZ*2;  // bytes
  int GB = 1, HB = 1;
  const int cfgs[7][2] = {{8,8},{4,8},{2,8},{1,8},{1,4},{1,2},{1,1}};
  for (int i = 0; i < 7; ++i){
    int gb = cfgs[i][0], hb = cfgs[i][1];
    size_t need = 4ull*(4ull*H_*NTOT + 64)           // coeffs + flag
                + 4ull*(size_t)gb*hb*LG              // nrm
                + 2ull*(size_t)gb*MSZ                // G (f16)
                + (size_t)gb*hb*REG;                 // chain regions
    if (need <= ws_size){ GB = gb; HB = hb; break; }
  }
  int lgHB = (HB==8)?3:((HB==4)?2:((HB==2)?1:0));
  int nbh = GB*HB;

  float* a0  = (float*)d_ws;
  float* a1  = a0 + H_*NTOT;
  float* dum = a1 + H_*NTOT;
  float* sdt = dum + H_*NTOT;
  int*  flag = (int*)(sdt + H_*NTOT);
  float* nrm = (float*)flag + 64;
  f16* G     = (f16*)(nrm + (size_t)nbh*LG);
  char* chainBase = (char*)(G + (size_t)GB*MSZ);

  k_sniff<<<1, 256, 0, stream>>>(dt, flag);
  k_nodecoef<<<(H_*NTOT + 255)/256, 256, 0, stream>>>(dt, dtb, flag, a0, a1, dum, sdt);

  for (int b0 = 0; b0 < BN; b0 += GB){
    for (int h0 = 0; h0 < H_; h0 += HB){
      k_zero<<<dim3(1025, nbh), 256, 0, stream>>>(chainBase, REG, nrm);
      int nthr = GB*EPG*HB;
      k_scatter<<<(nthr + 255)/256, 256, 0, stream>>>(ei, a0, a1, chainBase, REG, nrm,
                                                      b0, h0, lgHB, GB, nthr, Etot);
      k_norm2<<<dim3(32, 32, nbh), 256, 0, stream>>>(chainBase, REG, nrm, dum, b0, h0, HB);
      if (h0 == 0){
        dim3 gg(64, 64, GB);
        k_G<<<gg, 256, 0, stream>>>(Bm, Cm, flag, G, b0);
      }
      // chain schedule: S0; {S_{k+1}, U_k} fused x4; U_4.
      // S: L' = L@L (writes C and C^T).  U: O' = O@L' + O (B-operand = L'^T).
      int lA = 0, lAT = 1, lC = 2, lCT = 3, oA = 4, oC = 5;
      {
        dim3 gg(4, 4, nbh);
        k_gemm_fused<<<gg, 512, 131072, stream>>>(chainBase, REG, nbh, lA, lAT, lC, lCT,
                                                  0, 0, 0, 0);
      }
      for (int k = 0; k < 4; ++k){
        dim3 gg(4, 4, 2*nbh);
        k_gemm_fused<<<gg, 512, 131072, stream>>>(chainBase, REG,
                                                  nbh, lC, lCT, lA, lAT,    // S_{k+1}
                                                  nbh, oA, lCT, oC);        // U_k
        int tp;
        tp = lA; lA = lC; lC = tp;
        tp = lAT; lAT = lCT; lCT = tp;
        tp = oA; oA = oC; oC = tp;
      }
      {
        dim3 gg(4, 4, nbh);
        k_gemm_fused<<<gg, 512, 131072, stream>>>(chainBase, REG, 0, 0, 0, 0, 0,
                                                  nbh, oA, lCT, oC);        // U_4
        int tp = oA; oA = oC; oC = tp;
      }
      dim3 fg(64, nbh);
      k_final2<<<fg, 256, 0, stream>>>(chainBase, REG, oA, G, sdt, x, Dv, flag, d_out, b0, h0, HB);
    }
  }
}

// Round 2
// 2502.232 us; speedup vs baseline: 1.0675x; 1.0675x over previous
//
#include <hip/hip_runtime.h>
#include <hip/hip_bf16.h>

#define H_ 8
#define NTOT 8192
#define LG 1024
#define BN 8
#define HD 16
#define DSTATE 64
#define EPG 16384
#define MSZ (1024*1024)

typedef __hip_bfloat16 bf16;
typedef unsigned short ushort_t;
typedef _Float16 f16;
typedef __attribute__((ext_vector_type(8))) _Float16 half8;
typedef __attribute__((ext_vector_type(4))) _Float16 half4;
typedef __attribute__((ext_vector_type(4))) float f4v;

__device__ __forceinline__ float b2f(bf16 v){ return __bfloat162float(v); }
// stable softplus matching jax.nn.softplus = log1p(exp(z))
__device__ __forceinline__ float sp_(float z){
  return fmaxf(z, 0.f) + log1pf(expf(-fabsf(z)));
}
// dtype-flagged scalar load (uniform branch)
__device__ __forceinline__ float ldv(const void* p, size_t i, int f32){
  float v;
  if (f32) v = ((const float*)p)[i];
  else     v = b2f(((const bf16*)p)[i]);
  return v;
}
// async global->LDS, 16 bytes per lane
__device__ __forceinline__ void gl2lds16(const void* g, void* l){
  __builtin_amdgcn_global_load_lds((const __attribute__((address_space(1))) unsigned int*)g,
                                   (__attribute__((address_space(3))) unsigned int*)l,
                                   16, 0, 0);
}

// raw workgroup barrier with compiler-level memory fences on both sides
// (raw s_barrier does NOT get an automatic vmcnt(0) drain -> prefetch stays in flight)
#define BARC() do { asm volatile("" ::: "memory"); __builtin_amdgcn_s_barrier(); asm volatile("" ::: "memory"); } while(0)

// -------- dtype sniffer: bf16 N(0,1) data never has exponent>=140; f32-as-bf16 does.
__global__ void k_sniff(const void* __restrict__ dt, int* __restrict__ flag){
  const ushort_t* p = (const ushort_t*)dt;
  int tid = threadIdx.x;
  int bad = 0;
  for (int i = tid; i < 512; i += 256){
    int e = (p[i] >> 7) & 0xFF;
    if (e >= 140) bad = 1;
  }
  unsigned long long m = __ballot(bad != 0);
  __shared__ int anybad[4];
  if ((tid & 63) == 0) anybad[tid >> 6] = (m != 0ull) ? 1 : 0;
  __syncthreads();
  if (tid == 0) *flag = (anybad[0] | anybad[1] | anybad[2] | anybad[3]);
}

// -------- per-node coefficients. a0/a1 stored [n][h] (coalesced for k_scatter);
// dum/sdt stay [h][n] (coalesced for k_norm2/k_final2).
__global__ void k_nodecoef(const void* __restrict__ dt, const void* __restrict__ dtb,
                           const int* __restrict__ flag,
                           float* __restrict__ a0, float* __restrict__ a1,
                           float* __restrict__ dum, float* __restrict__ sdt){
  int idx = blockIdx.x*256 + threadIdx.x;
  if (idx >= H_*NTOT) return;
  int f32 = *flag;
  int h = idx / NTOT, n = idx - h*NTOT;
  float bias = ldv(dtb, h, f32);
  size_t base = (size_t)n*(4*H_) + h*4;
  float d0, d1, d2, d3;
  if (f32){
    const float* row = (const float*)dt + base;
    d0 = row[0]; d1 = row[1]; d2 = row[2]; d3 = row[3];
  } else {
    const bf16* row = (const bf16*)dt + base;
    d0 = b2f(row[0]); d1 = b2f(row[1]); d2 = b2f(row[2]); d3 = b2f(row[3]);
  }
  a0[(size_t)n*H_ + h] = -sp_(d0 + bias);
  a1[(size_t)n*H_ + h] = -sp_(d1 + bias);
  dum[idx] = expf(-sp_(d2 + bias));
  sdt[idx] = d3;
}

// -------- zero the per-bh fp32 scatter buffers (aliased at f16 matrix slots 2,3)
// plus the per-bh nrm row (x-block 1024).
__global__ __launch_bounds__(256) void k_zero(char* base, size_t regB, float* __restrict__ nrm){
  int bh = blockIdx.y;
  if (blockIdx.x < 1024){
    float* Mf = (float*)(base + (size_t)bh*regB) + MSZ;
    int i = blockIdx.x*1024 + threadIdx.x*4;
    *(float4*)(Mf + i) = make_float4(0.f,0.f,0.f,0.f);
  } else {
    int j = threadIdx.x*4;
    *(float4*)(nrm + (size_t)bh*LG + j) = make_float4(0.f,0.f,0.f,0.f);
  }
}

// -------- scatter edges into fp32 M = A^T (M[dl][sl] += attr), plus row-sum of A over sl
__global__ void k_scatter(const int* __restrict__ ei, const float* __restrict__ a0,
                          const float* __restrict__ a1, char* base, size_t regB,
                          float* __restrict__ nrm,
                          int b0, int h0, int lgHB, int GBp, int nthreads, int Etot){
  int t = blockIdx.x*256 + threadIdx.x;
  if (t >= nthreads) return;
  int HB = 1 << lgHB;
  int hl = t & (HB-1);
  int el = t >> lgHB;
  int e = b0*EPG + el;
  int src = ei[e], dst = ei[Etot + e];
  int g = src >> 10;
  if ((unsigned)(g - b0) >= (unsigned)GBp) return;
  int sl = src & 1023, dl = dst & 1023;
  int h = h0 + hl;
  float attr = expf(0.5f*(a0[(size_t)src*H_ + h] + a1[(size_t)dst*H_ + h]));
  int bhl = (g - b0)*HB + hl;
  float* Mf = (float*)(base + (size_t)bhl*regB) + MSZ;
  atomicAdd(&Mf[(size_t)dl*LG + sl], attr);
  atomicAdd(&nrm[bhl*LG + sl], attr);
}

// -------- fused normalize + transpose (32x32 tiles): from fp32 M write
// f16 L0 (slot 0), L0^T (slot 1), O0 = I+M (slot 4) in one pass.
__global__ __launch_bounds__(256) void k_norm2(char* base, size_t regB,
                            const float* __restrict__ nrm, const float* __restrict__ dum,
                            int b0, int h0, int HB){
  __shared__ ushort_t tb[32][33];
  int bh = blockIdx.z;
  int g = b0 + bh / HB, h = h0 + bh % HB;
  const float* Mf = (const float*)(base + (size_t)bh*regB) + MSZ;
  f16* L0  = (f16*)(base + (size_t)bh*regB);
  f16* L0T = L0 + MSZ;
  f16* O0  = L0 + (size_t)4*MSZ;
  int x0 = blockIdx.x*32, y0 = blockIdx.y*32;   // x: sl, y: dl
  int tx = threadIdx.x & 31, ty = threadIdx.x >> 5;  // 32 x 8
  int sl = x0 + tx;
  float denom = nrm[(size_t)bh*LG + sl] + dum[(size_t)h*NTOT + g*LG + sl] + 0.1f;
  float rden = 1.f / denom;
  #pragma unroll
  for (int i = 0; i < 32; i += 8){
    int dl = y0 + ty + i;
    float v = Mf[(size_t)dl*LG + sl] * rden;
    f16 hv = (f16)v;
    L0[(size_t)dl*LG + sl] = hv;
    O0[(size_t)dl*LG + sl] = (f16)(v + (dl == sl ? 1.f : 0.f));
    union { f16 h; ushort_t u; } cv; cv.h = hv;
    tb[tx][ty + i] = cv.u;                 // [sl-local][dl-local]
  }
  __syncthreads();
  #pragma unroll
  for (int i = 0; i < 32; i += 8){
    union { f16 h; ushort_t u; } cv; cv.u = tb[ty + i][tx];
    L0T[(size_t)(x0 + ty + i)*LG + y0 + tx] = cv.h;   // L0T[sl][dl]
  }
}

// -------- G[b][l][t] = sum_d C[b,l,d]*B[b,t,d]  -> stored f16
__global__ __launch_bounds__(256) void k_G(const void* __restrict__ Bm, const void* __restrict__ Cm,
                                           const int* __restrict__ flag,
                                           f16* __restrict__ G, int b0){
  int gl = blockIdx.z;
  int g = b0 + gl;
  int l0 = blockIdx.y*16, t0 = blockIdx.x*16;
  __shared__ float Cs[16][DSTATE+1];
  __shared__ float Bs[16][DSTATE+1];
  int tid = threadIdx.x;
  int f32 = *flag;
  if (f32){
    const float* Cf = (const float*)Cm;
    const float* Bf = (const float*)Bm;
    for (int i = tid; i < 16*DSTATE; i += 256){
      int r = i >> 6, d = i & 63;
      Cs[r][d] = Cf[(size_t)(g*LG + l0 + r)*DSTATE + d];
      Bs[r][d] = Bf[(size_t)(g*LG + t0 + r)*DSTATE + d];
    }
  } else {
    const bf16* Cb = (const bf16*)Cm;
    const bf16* Bb = (const bf16*)Bm;
    for (int i = tid; i < 16*DSTATE; i += 256){
      int r = i >> 6, d = i & 63;
      Cs[r][d] = b2f(Cb[(size_t)(g*LG + l0 + r)*DSTATE + d]);
      Bs[r][d] = b2f(Bb[(size_t)(g*LG + t0 + r)*DSTATE + d]);
    }
  }
  __syncthreads();
  int r = tid >> 4, c = tid & 15;
  float acc = 0.f;
  #pragma unroll
  for (int d = 0; d < DSTATE; ++d) acc = fmaf(Cs[r][d], Bs[c][d], acc);
  G[(size_t)gl*MSZ + (size_t)(l0+r)*LG + t0 + c] = (f16)acc;
}

// -------- r14: 256x256-tile 8-phase fused GEMM (r13 schedule) + restored
// XCD-pinned block mapping (r10's): s = blockIdx.x + 8*blockIdx.z so the
// linearized block id has bh%8 in the fastest position -> XCD = bh%8
// consistently across ALL chain dispatches. Each XCD's 4MB L2 keeps its own
// bh's A/B/C panels resident across the whole chain (r13's gg(4,4,T) mapping
// spread every matrix over all XCDs: FETCH 80->213MB, HBM-bound regression).
// Schedule (unchanged from r13): 512 thr = 8 waves (2Mx4N), per-wave 128x64,
// acc[8][4]; LDS ring of 8 x 16KB half-slots (128KB dynamic); counted
// s_waitcnt vmcnt(4) once per K-tile (never 0 mid-loop); raw s_barrier;
// XOR-swizzled gl2lds source + matching read swizzle (0 bank conflicts);
// s_setprio(1) around each 16-MFMA cluster.
__global__ __launch_bounds__(512, 2) void k_gemm_fused(char* base, size_t regB,
    int nS, int iAs, int iBTs, int iCs, int iCTs,
    int nU, int iAu, int iBTu, int iCu){
  extern __shared__ char lds[];
  int T = nS + nU;
  int s = blockIdx.x + 8*blockIdx.z;
  if (s >= T) return;
  int isS = (s < nS) ? 1 : 0;
  int bh  = isS ? s : (s - nS);
  int iA  = isS ? iAs : iAu;
  int iBT = isS ? iBTs : iBTu;
  int iC  = isS ? iCs : iCu;
  int iCT = isS ? iCTs : -1;
  int addA = 1 - isS;
  char* reg = base + (size_t)bh*regB;
  const f16* Ab = (const f16*)reg + (size_t)iA*MSZ;
  const f16* Bb = (const f16*)reg + (size_t)iBT*MSZ;
  f16* Cb = (f16*)reg + (size_t)iC*MSZ;
  int y = blockIdx.y;
  int i0 = (y >> 2)*256, j0 = (y & 3)*256;
  int tid = threadIdx.x;
  int lane = tid & 63, wv = tid >> 6;          // 8 waves
  int wm = wv >> 2, wn = wv & 3;               // 2 x 4 wave grid
  int m16 = lane & 15, q = lane >> 4;
  int rswz  = m16*128 + ((q ^ (m16 & 7)) << 4);  // ks=0 swizzled lane offset
  int rswz1 = rswz ^ 64;                          // ks=1 (chunk +4 under XOR)
  int bcol = (wn & 1) << 13;                   // col-base byte offset in B half-slot
  // staging constants: thread t covers row sr (within 64-row group), chunk sc
  int sr = tid >> 3;
  int sc = (tid & 7) ^ (sr & 7);               // pre-swizzled source chunk

  auto ISSUE = [&](int h){                     // stage half-tile h (uniform h)
    if (h >= 64) return;
    int j = h & 3;
    const f16* M = (j < 2) ? Bb : Ab;
    int rb = ((j < 2) ? j0 : i0) + ((j & 1) << 7);
    const f16* src = M + (size_t)(rb + sr)*LG + ((h >> 2) << 6) + sc*8;
    char* dst = lds + ((h & 7) << 14) + tid*16;
    gl2lds16(src, dst);                        // rows rb+0..63
    gl2lds16(src + (size_t)64*LG, dst + 8192); // rows rb+64..127
  };

  // prologue: tile0 (h0-3) + tile1 B halves (h4,5); wait tile0 (4 newest ok)
  ISSUE(0); ISSUE(1); ISSUE(2); ISSUE(3); ISSUE(4); ISSUE(5);
  f4v acc[8][4] = {};
  half8 af[4], bfr[2][4];
  asm volatile("s_waitcnt vmcnt(4)" ::: "memory");
  BARC();

  for (int kt = 0; kt < 16; ++kt){
    int sb = (kt & 1) << 2;
    const char* Asl = lds + ((sb + 2 + wm) << 14);
    const char* Bsl = lds + ((sb + (wn >> 1)) << 14) + bcol;
    int h0 = kt*4 + 6;
    // ---- phase 0: af(mt0-3, ks0) + bf[0]; issue h0 (next-tile A0)
    #pragma unroll
    for (int t = 0; t < 4; ++t) af[t] = *(const half8*)(Asl + t*2048 + rswz);
    #pragma unroll
    for (int t = 0; t < 4; ++t) bfr[0][t] = *(const half8*)(Bsl + t*2048 + rswz);
    ISSUE(h0);
    BARC();
    asm volatile("s_waitcnt lgkmcnt(0)" ::: "memory");
    __builtin_amdgcn_s_setprio(1);
    #pragma unroll
    for (int mt = 0; mt < 4; ++mt)
      #pragma unroll
      for (int nt = 0; nt < 4; ++nt)
        acc[mt][nt] = __builtin_amdgcn_mfma_f32_16x16x32_f16(af[mt], bfr[0][nt], acc[mt][nt], 0, 0, 0);
    __builtin_amdgcn_s_setprio(0);
    BARC();
    // ---- phase 1: af(mt4-7, ks0) + bf[1]; issue h0+1 (next-tile A1)
    #pragma unroll
    for (int t = 0; t < 4; ++t) af[t] = *(const half8*)(Asl + 8192 + t*2048 + rswz);
    #pragma unroll
    for (int t = 0; t < 4; ++t) bfr[1][t] = *(const half8*)(Bsl + t*2048 + rswz1);
    ISSUE(h0 + 1);
    BARC();
    asm volatile("s_waitcnt lgkmcnt(0)" ::: "memory");
    __builtin_amdgcn_s_setprio(1);
    #pragma unroll
    for (int mt = 0; mt < 4; ++mt)
      #pragma unroll
      for (int nt = 0; nt < 4; ++nt)
        acc[4 + mt][nt] = __builtin_amdgcn_mfma_f32_16x16x32_f16(af[mt], bfr[0][nt], acc[4 + mt][nt], 0, 0, 0);
    __builtin_amdgcn_s_setprio(0);
    BARC();
    // ---- phase 2: af(mt0-3, ks1); issue h0+2 (tile+2 B0, overwrites retired B0)
    #pragma unroll
    for (int t = 0; t < 4; ++t) af[t] = *(const half8*)(Asl + t*2048 + rswz1);
    ISSUE(h0 + 2);
    BARC();
    asm volatile("s_waitcnt lgkmcnt(0)" ::: "memory");
    __builtin_amdgcn_s_setprio(1);
    #pragma unroll
    for (int mt = 0; mt < 4; ++mt)
      #pragma unroll
      for (int nt = 0; nt < 4; ++nt)
        acc[mt][nt] = __builtin_amdgcn_mfma_f32_16x16x32_f16(af[mt], bfr[1][nt], acc[mt][nt], 0, 0, 0);
    __builtin_amdgcn_s_setprio(0);
    BARC();
    // ---- phase 3: af(mt4-7, ks1); issue h0+3 (tile+2 B1); boundary wait
    #pragma unroll
    for (int t = 0; t < 4; ++t) af[t] = *(const half8*)(Asl + 8192 + t*2048 + rswz1);
    ISSUE(h0 + 3);
    BARC();
    asm volatile("s_waitcnt lgkmcnt(0)" ::: "memory");
    __builtin_amdgcn_s_setprio(1);
    #pragma unroll
    for (int mt = 0; mt < 4; ++mt)
      #pragma unroll
      for (int nt = 0; nt < 4; ++nt)
        acc[4 + mt][nt] = __builtin_amdgcn_mfma_f32_16x16x32_f16(af[mt], bfr[1][nt], acc[4 + mt][nt], 0, 0, 0);
    __builtin_amdgcn_s_setprio(0);
    if (kt < 14)       asm volatile("s_waitcnt vmcnt(4)" ::: "memory");
    else if (kt == 14) asm volatile("s_waitcnt vmcnt(0)" ::: "memory");
    BARC();
  }

  f16* CT = (f16*)reg + (size_t)((iCT < 0) ? iC : iCT)*MSZ;
  // epilogue: D lane mapping col=lane&15, row=(lane>>4)*4+r (same as r10)
  #pragma unroll
  for (int mt = 0; mt < 8; ++mt){
    #pragma unroll
    for (int nt = 0; nt < 4; ++nt){
      int gr0 = i0 + wm*128 + mt*16 + q*4;
      int gc  = j0 + wn*64 + nt*16 + m16;
      half4 tv;
      #pragma unroll
      for (int r = 0; r < 4; ++r){
        float v = acc[mt][nt][r];
        if (addA) v += (float)Ab[(size_t)(gr0 + r)*LG + gc];
        f16 hv = (f16)v;
        tv[r] = hv;
        Cb[(size_t)(gr0 + r)*LG + gc] = hv;
      }
      if (iCT >= 0)
        *(half4*)&CT[(size_t)gc*LG + gr0] = tv;
    }
  }
}

// -------- final: y[l,d] = sum_t O[l,t]*s[t]*G[l,t]*x[t,d] + x[l,d]*D[h]
// block: 16 l-rows x one bh; t-chunked coef tile in LDS; thread = (l, d)
// (r10's proven single-pass version — the r12 two-stage split was neutral-to-worse)
__global__ __launch_bounds__(256) void k_final2(char* base, size_t regB, int iO,
    const f16* __restrict__ Gh, const float* __restrict__ sdt,
    const void* __restrict__ x, const void* __restrict__ Dv,
    const int* __restrict__ flag, void* __restrict__ out,
    int b0, int h0, int HB){
  __shared__ float coef[16][257];
  int bh = blockIdx.y;
  int gl = bh / HB, g = b0 + gl, h = h0 + bh % HB;
  int L0r = blockIdx.x*16;
  int tid = threadIdx.x;
  int lr = tid >> 4, ts = tid & 15;   // phase1: (row lr, t-seg ts); phase2: (row lr, d=ts)
  int f32 = *flag;
  const f16* Orow = (const f16*)(base + (size_t)bh*regB) + (size_t)iO*MSZ + (size_t)(L0r+lr)*LG;
  const f16* Grow = Gh + (size_t)gl*MSZ + (size_t)(L0r+lr)*LG;
  const float* srow = sdt + (size_t)h*NTOT + g*LG;
  float acc = 0.f;
  for (int tc = 0; tc < LG; tc += 256){
    int tb = tc + ts*16;
    __syncthreads();
    half8 o0 = *(const half8*)&Orow[tb];
    half8 o1 = *(const half8*)&Orow[tb + 8];
    half8 g0 = *(const half8*)&Grow[tb];
    half8 g1 = *(const half8*)&Grow[tb + 8];
    #pragma unroll
    for (int j = 0; j < 8; ++j){
      coef[lr][ts*16 + j]     = (float)o0[j] * (float)g0[j] * srow[tb + j];
      coef[lr][ts*16 + 8 + j] = (float)o1[j] * (float)g1[j] * srow[tb + 8 + j];
    }
    __syncthreads();
    if (f32){
      const float* xf = (const float*)x + (size_t)(g*LG + tc)*128 + h*HD + ts;
      for (int t = 0; t < 256; ++t)
        acc = fmaf(coef[lr][t], xf[(size_t)t*128], acc);
    } else {
      const bf16* xb = (const bf16*)x + (size_t)(g*LG + tc)*128 + h*HD + ts;
      for (int t = 0; t < 256; ++t)
        acc = fmaf(coef[lr][t], b2f(xb[(size_t)t*128]), acc);
    }
  }
  int l = L0r + lr, d = ts;
  float xs = ldv(x, (size_t)(g*LG + l)*128 + h*HD + d, f32);
  float dv = ldv(Dv, h, f32);
  float v = acc + xs*dv;
  size_t off = (size_t)(g*LG + l)*128 + d*H_ + h;
  if (f32) ((float*)out)[off] = v;
  else     ((bf16*)out)[off] = __float2bfloat16(v);
}

extern "C" void kernel_launch(void* const* d_in, const int* in_sizes, int n_in,
                              void* d_out, int out_size, void* d_ws, size_t ws_size,
                              hipStream_t stream){
  const void* x   = d_in[0];
  const void* Bm  = d_in[1];
  const void* Cm  = d_in[2];
  const void* dt  = d_in[3];
  const void* dtb = d_in[4];
  const void* Dv  = d_in[5];
  const int*  ei  = (const int*)d_in[6];
  int Etot = in_sizes[6] / 2;  // 131072

  // allow 128 KiB dynamic LDS for the GEMM (once per process; host-side, capture-safe)
  static int attrDone = 0;
  if (!attrDone){
    hipFuncSetAttribute(reinterpret_cast<const void*>(k_gemm_fused),
                        hipFuncAttributeMaxDynamicSharedMemorySize, 131072);
    attrDone = 1;
  }

  // per-(b,h) chain region: 6 f16 matrices (12 MB):
  //   slots 0-3: L/LT ping-pong pairs, 4,5: O ping/pong
  //   fp32 scatter buffer (4 MB) aliases slots 2+3 (dead before first GEMM writes them)
  const size_t REG = (size_t)6*MSZ*2;  // bytes
  int GB = 1, HB = 1;
  const int cfgs[7][2] = {{8,8},{4,8},{2,8},{1,8},{1,4},{1,2},{1,1}};
  for (int i = 0; i < 7; ++i){
    int gb = cfgs[i][0], hb = cfgs[i][1];
    size_t need = 4ull*(4ull*H_*NTOT + 64)           // coeffs + flag
                + 4ull*(size_t)gb*hb*LG              // nrm
                + 2ull*(size_t)gb*MSZ                // G (f16)
                + (size_t)gb*hb*REG;                 // chain regions
    if (need <= ws_size){ GB = gb; HB = hb; break; }
  }
  int lgHB = (HB==8)?3:((HB==4)?2:((HB==2)?1:0));
  int nbh = GB*HB;

  float* a0  = (float*)d_ws;
  float* a1  = a0 + H_*NTOT;
  float* dum = a1 + H_*NTOT;
  float* sdt = dum + H_*NTOT;
  int*  flag = (int*)(sdt + H_*NTOT);
  float* nrm = (float*)flag + 64;
  f16* G     = (f16*)(nrm + (size_t)nbh*LG);
  char* chainBase = (char*)(G + (size_t)GB*MSZ);

  k_sniff<<<1, 256, 0, stream>>>(dt, flag);
  k_nodecoef<<<(H_*NTOT + 255)/256, 256, 0, stream>>>(dt, dtb, flag, a0, a1, dum, sdt);

  for (int b0 = 0; b0 < BN; b0 += GB){
    for (int h0 = 0; h0 < H_; h0 += HB){
      k_zero<<<dim3(1025, nbh), 256, 0, stream>>>(chainBase, REG, nrm);
      int nthr = GB*EPG*HB;
      k_scatter<<<(nthr + 255)/256, 256, 0, stream>>>(ei, a0, a1, chainBase, REG, nrm,
                                                      b0, h0, lgHB, GB, nthr, Etot);
      k_norm2<<<dim3(32, 32, nbh), 256, 0, stream>>>(chainBase, REG, nrm, dum, b0, h0, HB);
      if (h0 == 0){
        dim3 gg(64, 64, GB);
        k_G<<<gg, 256, 0, stream>>>(Bm, Cm, flag, G, b0);
      }
      // chain schedule: S0; {S_{k+1}, U_k} fused x4; U_4.
      // S: L' = L@L (writes C and C^T).  U: O' = O@L' + O (B-operand = L'^T).
      int lA = 0, lAT = 1, lC = 2, lCT = 3, oA = 4, oC = 5;
      {
        int T = nbh;
        dim3 gg(8, 16, (T + 7)/8);
        k_gemm_fused<<<gg, 512, 131072, stream>>>(chainBase, REG, nbh, lA, lAT, lC, lCT,
                                                  0, 0, 0, 0);
      }
      for (int k = 0; k < 4; ++k){
        int T = 2*nbh;
        dim3 gg(8, 16, (T + 7)/8);
        k_gemm_fused<<<gg, 512, 131072, stream>>>(chainBase, REG,
                                                  nbh, lC, lCT, lA, lAT,    // S_{k+1}
                                                  nbh, oA, lCT, oC);        // U_k
        int tp;
        tp = lA; lA = lC; lC = tp;
        tp = lAT; lAT = lCT; lCT = tp;
        tp = oA; oA = oC; oC = tp;
      }
      {
        int T = nbh;
        dim3 gg(8, 16, (T + 7)/8);
        k_gemm_fused<<<gg, 512, 131072, stream>>>(chainBase, REG, 0, 0, 0, 0, 0,
                                                  nbh, oA, lCT, oC);        // U_4
        int tp = oA; oA = oC; oC = tp;
      }
      dim3 fg(64, nbh);
      k_final2<<<fg, 256, 0, stream>>>(chainBase, REG, oA, G, sdt, x, Dv, flag, d_out, b0, h0, HB);
    }
  }
}

// Round 3
// 2249.939 us; speedup vs baseline: 1.1872x; 1.1121x over previous
//
#include <hip/hip_runtime.h>
#include <hip/hip_bf16.h>

#define H_ 8
#define NTOT 8192
#define LG 1024
#define BN 8
#define HD 16
#define DSTATE 64
#define EPG 16384
#define MSZ (1024*1024)

typedef __hip_bfloat16 bf16;
typedef unsigned short ushort_t;
typedef _Float16 f16;
typedef __attribute__((ext_vector_type(8))) _Float16 half8;
typedef __attribute__((ext_vector_type(4))) _Float16 half4;
typedef __attribute__((ext_vector_type(4))) float f4v;

__device__ __forceinline__ float b2f(bf16 v){ return __bfloat162float(v); }
// stable softplus matching jax.nn.softplus = log1p(exp(z))
__device__ __forceinline__ float sp_(float z){
  return fmaxf(z, 0.f) + log1pf(expf(-fabsf(z)));
}
// dtype-flagged scalar load (uniform branch)
__device__ __forceinline__ float ldv(const void* p, size_t i, int f32){
  float v;
  if (f32) v = ((const float*)p)[i];
  else     v = b2f(((const bf16*)p)[i]);
  return v;
}
// async global->LDS, 16 bytes per lane
__device__ __forceinline__ void gl2lds16(const void* g, void* l){
  __builtin_amdgcn_global_load_lds((const __attribute__((address_space(1))) unsigned int*)g,
                                   (__attribute__((address_space(3))) unsigned int*)l,
                                   16, 0, 0);
}

// raw workgroup barrier with compiler-level memory fences on both sides
// (raw s_barrier does NOT get an automatic vmcnt(0) drain -> prefetch stays in flight)
#define BARC() do { asm volatile("" ::: "memory"); __builtin_amdgcn_s_barrier(); asm volatile("" ::: "memory"); } while(0)

// -------- dtype sniffer: bf16 N(0,1) data never has exponent>=140; f32-as-bf16 does.
__global__ void k_sniff(const void* __restrict__ dt, int* __restrict__ flag){
  const ushort_t* p = (const ushort_t*)dt;
  int tid = threadIdx.x;
  int bad = 0;
  for (int i = tid; i < 512; i += 256){
    int e = (p[i] >> 7) & 0xFF;
    if (e >= 140) bad = 1;
  }
  unsigned long long m = __ballot(bad != 0);
  __shared__ int anybad[4];
  if ((tid & 63) == 0) anybad[tid >> 6] = (m != 0ull) ? 1 : 0;
  __syncthreads();
  if (tid == 0) *flag = (anybad[0] | anybad[1] | anybad[2] | anybad[3]);
}

// -------- per-node coefficients. a0/a1 stored [n][h] (coalesced for k_scatter);
// dum/sdt stay [h][n] (coalesced for k_norm2/k_final2).
__global__ void k_nodecoef(const void* __restrict__ dt, const void* __restrict__ dtb,
                           const int* __restrict__ flag,
                           float* __restrict__ a0, float* __restrict__ a1,
                           float* __restrict__ dum, float* __restrict__ sdt){
  int idx = blockIdx.x*256 + threadIdx.x;
  if (idx >= H_*NTOT) return;
  int f32 = *flag;
  int h = idx / NTOT, n = idx - h*NTOT;
  float bias = ldv(dtb, h, f32);
  size_t base = (size_t)n*(4*H_) + h*4;
  float d0, d1, d2, d3;
  if (f32){
    const float* row = (const float*)dt + base;
    d0 = row[0]; d1 = row[1]; d2 = row[2]; d3 = row[3];
  } else {
    const bf16* row = (const bf16*)dt + base;
    d0 = b2f(row[0]); d1 = b2f(row[1]); d2 = b2f(row[2]); d3 = b2f(row[3]);
  }
  a0[(size_t)n*H_ + h] = -sp_(d0 + bias);
  a1[(size_t)n*H_ + h] = -sp_(d1 + bias);
  dum[idx] = expf(-sp_(d2 + bias));
  sdt[idx] = d3;
}

// -------- zero the per-bh fp32 scatter buffers (aliased at f16 matrix slots 2,3)
// plus the per-bh nrm row (x-block 1024).
__global__ __launch_bounds__(256) void k_zero(char* base, size_t regB, float* __restrict__ nrm){
  int bh = blockIdx.y;
  if (blockIdx.x < 1024){
    float* Mf = (float*)(base + (size_t)bh*regB) + MSZ;
    int i = blockIdx.x*1024 + threadIdx.x*4;
    *(float4*)(Mf + i) = make_float4(0.f,0.f,0.f,0.f);
  } else {
    int j = threadIdx.x*4;
    *(float4*)(nrm + (size_t)bh*LG + j) = make_float4(0.f,0.f,0.f,0.f);
  }
}

// -------- scatter edges into fp32 M = A^T (M[dl][sl] += attr), plus row-sum of A over sl
__global__ void k_scatter(const int* __restrict__ ei, const float* __restrict__ a0,
                          const float* __restrict__ a1, char* base, size_t regB,
                          float* __restrict__ nrm,
                          int b0, int h0, int lgHB, int GBp, int nthreads, int Etot){
  int t = blockIdx.x*256 + threadIdx.x;
  if (t >= nthreads) return;
  int HB = 1 << lgHB;
  int hl = t & (HB-1);
  int el = t >> lgHB;
  int e = b0*EPG + el;
  int src = ei[e], dst = ei[Etot + e];
  int g = src >> 10;
  if ((unsigned)(g - b0) >= (unsigned)GBp) return;
  int sl = src & 1023, dl = dst & 1023;
  int h = h0 + hl;
  float attr = expf(0.5f*(a0[(size_t)src*H_ + h] + a1[(size_t)dst*H_ + h]));
  int bhl = (g - b0)*HB + hl;
  float* Mf = (float*)(base + (size_t)bhl*regB) + MSZ;
  atomicAdd(&Mf[(size_t)dl*LG + sl], attr);
  atomicAdd(&nrm[bhl*LG + sl], attr);
}

// -------- fused normalize + transpose (32x32 tiles): from fp32 M write
// f16 L0 (slot 0), L0^T (slot 1), O0 = I+M (slot 4) in one pass.
__global__ __launch_bounds__(256) void k_norm2(char* base, size_t regB,
                            const float* __restrict__ nrm, const float* __restrict__ dum,
                            int b0, int h0, int HB){
  __shared__ ushort_t tb[32][33];
  int bh = blockIdx.z;
  int g = b0 + bh / HB, h = h0 + bh % HB;
  const float* Mf = (const float*)(base + (size_t)bh*regB) + MSZ;
  f16* L0  = (f16*)(base + (size_t)bh*regB);
  f16* L0T = L0 + MSZ;
  f16* O0  = L0 + (size_t)4*MSZ;
  int x0 = blockIdx.x*32, y0 = blockIdx.y*32;   // x: sl, y: dl
  int tx = threadIdx.x & 31, ty = threadIdx.x >> 5;  // 32 x 8
  int sl = x0 + tx;
  float denom = nrm[(size_t)bh*LG + sl] + dum[(size_t)h*NTOT + g*LG + sl] + 0.1f;
  float rden = 1.f / denom;
  #pragma unroll
  for (int i = 0; i < 32; i += 8){
    int dl = y0 + ty + i;
    float v = Mf[(size_t)dl*LG + sl] * rden;
    f16 hv = (f16)v;
    L0[(size_t)dl*LG + sl] = hv;
    O0[(size_t)dl*LG + sl] = (f16)(v + (dl == sl ? 1.f : 0.f));
    union { f16 h; ushort_t u; } cv; cv.h = hv;
    tb[tx][ty + i] = cv.u;                 // [sl-local][dl-local]
  }
  __syncthreads();
  #pragma unroll
  for (int i = 0; i < 32; i += 8){
    union { f16 h; ushort_t u; } cv; cv.u = tb[ty + i][tx];
    L0T[(size_t)(x0 + ty + i)*LG + y0 + tx] = cv.h;   // L0T[sl][dl]
  }
}

// -------- G[b][l][t] = sum_d C[b,l,d]*B[b,t,d]  -> stored f16
__global__ __launch_bounds__(256) void k_G(const void* __restrict__ Bm, const void* __restrict__ Cm,
                                           const int* __restrict__ flag,
                                           f16* __restrict__ G, int b0){
  int gl = blockIdx.z;
  int g = b0 + gl;
  int l0 = blockIdx.y*16, t0 = blockIdx.x*16;
  __shared__ float Cs[16][DSTATE+1];
  __shared__ float Bs[16][DSTATE+1];
  int tid = threadIdx.x;
  int f32 = *flag;
  if (f32){
    const float* Cf = (const float*)Cm;
    const float* Bf = (const float*)Bm;
    for (int i = tid; i < 16*DSTATE; i += 256){
      int r = i >> 6, d = i & 63;
      Cs[r][d] = Cf[(size_t)(g*LG + l0 + r)*DSTATE + d];
      Bs[r][d] = Bf[(size_t)(g*LG + t0 + r)*DSTATE + d];
    }
  } else {
    const bf16* Cb = (const bf16*)Cm;
    const bf16* Bb = (const bf16*)Bm;
    for (int i = tid; i < 16*DSTATE; i += 256){
      int r = i >> 6, d = i & 63;
      Cs[r][d] = b2f(Cb[(size_t)(g*LG + l0 + r)*DSTATE + d]);
      Bs[r][d] = b2f(Bb[(size_t)(g*LG + t0 + r)*DSTATE + d]);
    }
  }
  __syncthreads();
  int r = tid >> 4, c = tid & 15;
  float acc = 0.f;
  #pragma unroll
  for (int d = 0; d < DSTATE; ++d) acc = fmaf(Cs[r][d], Bs[c][d], acc);
  G[(size_t)gl*MSZ + (size_t)(l0+r)*LG + t0 + c] = (f16)acc;
}

// -------- r15: 256x256 tile, 1024 threads = 16 waves (4Mx4N), per-wave 64x64
// (acc[4][4] = 64 VGPR -> fits 128-VGPR budget for 4 waves/SIMD = 16 waves/CU,
// 2x r14's parallelism). BK=32: halves of 8KB (128 rows x 32k); ring of 16
// slots = 128KB LDS -> slot = h&15 (power-of-2), 3-K-tile prefetch lead
// (~1800cyc > 900cyc HBM latency). ONE raw barrier per K-step: tile kt's
// ISSUE overwrites tile kt-1's slots, whose reads completed (lgkmcnt before
// MFMA) before the end-of-(kt-1) barrier -> safe with a single barrier.
// Counted vmcnt(4) per tile (2 loads/thread/tile, 2 tiles in flight), never
// 0 mid-loop. XOR swizzle for 64B rows: slot = q ^ ((row>>1)&3) -> <=2-way
// (free) conflicts per 16-lane phase. XCD pinning kept: s = bid.x + 8*bid.z.
__global__ __launch_bounds__(1024, 4) void k_gemm_fused(char* base, size_t regB,
    int nS, int iAs, int iBTs, int iCs, int iCTs,
    int nU, int iAu, int iBTu, int iCu){
  extern __shared__ char lds[];
  int T = nS + nU;
  int s = blockIdx.x + 8*blockIdx.z;
  if (s >= T) return;
  int isS = (s < nS) ? 1 : 0;
  int bh  = isS ? s : (s - nS);
  int iA  = isS ? iAs : iAu;
  int iBT = isS ? iBTs : iBTu;
  int iC  = isS ? iCs : iCu;
  int iCT = isS ? iCTs : -1;
  int addA = 1 - isS;
  char* reg = base + (size_t)bh*regB;
  const f16* Ab = (const f16*)reg + (size_t)iA*MSZ;
  const f16* Bb = (const f16*)reg + (size_t)iBT*MSZ;
  f16* Cb = (f16*)reg + (size_t)iC*MSZ;
  int y = blockIdx.y;
  int i0 = (y >> 2)*256, j0 = (y & 3)*256;
  int tid = threadIdx.x;
  int lane = tid & 63, wv = tid >> 6;          // 16 waves
  int wm = wv >> 2, wn = wv & 3;               // 4 x 4 wave grid, per-wave 64x64
  int m16 = lane & 15, q = lane >> 4;
  int swz = (q ^ ((m16 >> 1) & 3)) << 4;       // 16B slot within 64B row
  int aoff = (((wm & 1) << 6) + m16)*64 + swz; // byte offset in A half (row*64 + slot)
  int boff = (((wn & 1) << 6) + m16)*64 + swz; // byte offset in B half
  // staging: thread tl covers row sr (0..127), chunk slot tl&3, source chunk sc
  int tl = tid & 511;
  int sr = tl >> 2;
  int sc = (tl & 3) ^ ((sr >> 1) & 3);

  // half h (0..127): K-tile = h>>2, kind j=h&3: 0=A0,1=A1,2=B0,3=B1.
  // ISSUE2 stages halves hA (waves 0-7) and hA+1 (waves 8-15): 1 load/thread.
  auto ISSUE2 = [&](int hA){
    if (hA >= 128) return;
    int h = (tid < 512) ? hA : (hA + 1);
    int j = h & 3;
    int kt2 = h >> 2;
    const f16* M = (j < 2) ? Ab : Bb;
    int rb = ((j < 2) ? i0 : j0) + ((j & 1) << 7);
    const f16* src = M + (size_t)(rb + sr)*LG + kt2*32 + sc*8;
    char* dst = lds + ((h & 15) << 13) + tl*16;
    gl2lds16(src, dst);
  };

  // prologue: stage tiles 0,1,2 (6 loads/thread); wait tile 0 (newest 4 = tiles 1,2)
  ISSUE2(0); ISSUE2(2);
  ISSUE2(4); ISSUE2(6);
  ISSUE2(8); ISSUE2(10);
  f4v acc[4][4] = {};
  half8 af[4], bfr[4];
  asm volatile("s_waitcnt vmcnt(4)" ::: "memory");
  BARC();

  for (int kt = 0; kt < 32; ++kt){
    int sb = (kt & 3) << 2;
    const char* Asl = lds + ((sb + (wm >> 1)) << 13);
    const char* Bsl = lds + ((sb + 2 + (wn >> 1)) << 13);
    #pragma unroll
    for (int t = 0; t < 4; ++t) af[t]  = *(const half8*)(Asl + aoff + t*1024);
    #pragma unroll
    for (int t = 0; t < 4; ++t) bfr[t] = *(const half8*)(Bsl + boff + t*1024);
    int hn = 4*(kt + 3);
    ISSUE2(hn); ISSUE2(hn + 2);                // overwrites tile kt-1's slots (safe)
    asm volatile("s_waitcnt lgkmcnt(0)" ::: "memory");
    __builtin_amdgcn_s_setprio(1);
    #pragma unroll
    for (int mt = 0; mt < 4; ++mt)
      #pragma unroll
      for (int nt = 0; nt < 4; ++nt)
        acc[mt][nt] = __builtin_amdgcn_mfma_f32_16x16x32_f16(af[mt], bfr[nt], acc[mt][nt], 0, 0, 0);
    __builtin_amdgcn_s_setprio(0);
    // boundary: ensure tile kt+1 staged before next iter's reads
    if (kt <= 28)      asm volatile("s_waitcnt vmcnt(4)" ::: "memory");
    else if (kt == 29) asm volatile("s_waitcnt vmcnt(2)" ::: "memory");
    else if (kt == 30) asm volatile("s_waitcnt vmcnt(0)" ::: "memory");
    BARC();
  }

  f16* CT = (f16*)reg + (size_t)((iCT < 0) ? iC : iCT)*MSZ;
  // epilogue: D lane mapping col=lane&15, row=(lane>>4)*4+r
  #pragma unroll
  for (int mt = 0; mt < 4; ++mt){
    #pragma unroll
    for (int nt = 0; nt < 4; ++nt){
      int gr0 = i0 + wm*64 + mt*16 + q*4;
      int gc  = j0 + wn*64 + nt*16 + m16;
      half4 tv;
      #pragma unroll
      for (int r = 0; r < 4; ++r){
        float v = acc[mt][nt][r];
        if (addA) v += (float)Ab[(size_t)(gr0 + r)*LG + gc];
        f16 hv = (f16)v;
        tv[r] = hv;
        Cb[(size_t)(gr0 + r)*LG + gc] = hv;
      }
      if (iCT >= 0)
        *(half4*)&CT[(size_t)gc*LG + gr0] = tv;
    }
  }
}

// -------- final: y[l,d] = sum_t O[l,t]*s[t]*G[l,t]*x[t,d] + x[l,d]*D[h]
// block: 16 l-rows x one bh; t-chunked coef tile in LDS; thread = (l, d)
// (r10's proven single-pass version — the r12 two-stage split was neutral-to-worse)
__global__ __launch_bounds__(256) void k_final2(char* base, size_t regB, int iO,
    const f16* __restrict__ Gh, const float* __restrict__ sdt,
    const void* __restrict__ x, const void* __restrict__ Dv,
    const int* __restrict__ flag, void* __restrict__ out,
    int b0, int h0, int HB){
  __shared__ float coef[16][257];
  int bh = blockIdx.y;
  int gl = bh / HB, g = b0 + gl, h = h0 + bh % HB;
  int L0r = blockIdx.x*16;
  int tid = threadIdx.x;
  int lr = tid >> 4, ts = tid & 15;   // phase1: (row lr, t-seg ts); phase2: (row lr, d=ts)
  int f32 = *flag;
  const f16* Orow = (const f16*)(base + (size_t)bh*regB) + (size_t)iO*MSZ + (size_t)(L0r+lr)*LG;
  const f16* Grow = Gh + (size_t)gl*MSZ + (size_t)(L0r+lr)*LG;
  const float* srow = sdt + (size_t)h*NTOT + g*LG;
  float acc = 0.f;
  for (int tc = 0; tc < LG; tc += 256){
    int tb = tc + ts*16;
    __syncthreads();
    half8 o0 = *(const half8*)&Orow[tb];
    half8 o1 = *(const half8*)&Orow[tb + 8];
    half8 g0 = *(const half8*)&Grow[tb];
    half8 g1 = *(const half8*)&Grow[tb + 8];
    #pragma unroll
    for (int j = 0; j < 8; ++j){
      coef[lr][ts*16 + j]     = (float)o0[j] * (float)g0[j] * srow[tb + j];
      coef[lr][ts*16 + 8 + j] = (float)o1[j] * (float)g1[j] * srow[tb + 8 + j];
    }
    __syncthreads();
    if (f32){
      const float* xf = (const float*)x + (size_t)(g*LG + tc)*128 + h*HD + ts;
      for (int t = 0; t < 256; ++t)
        acc = fmaf(coef[lr][t], xf[(size_t)t*128], acc);
    } else {
      const bf16* xb = (const bf16*)x + (size_t)(g*LG + tc)*128 + h*HD + ts;
      for (int t = 0; t < 256; ++t)
        acc = fmaf(coef[lr][t], b2f(xb[(size_t)t*128]), acc);
    }
  }
  int l = L0r + lr, d = ts;
  float xs = ldv(x, (size_t)(g*LG + l)*128 + h*HD + d, f32);
  float dv = ldv(Dv, h, f32);
  float v = acc + xs*dv;
  size_t off = (size_t)(g*LG + l)*128 + d*H_ + h;
  if (f32) ((float*)out)[off] = v;
  else     ((bf16*)out)[off] = __float2bfloat16(v);
}

extern "C" void kernel_launch(void* const* d_in, const int* in_sizes, int n_in,
                              void* d_out, int out_size, void* d_ws, size_t ws_size,
                              hipStream_t stream){
  const void* x   = d_in[0];
  const void* Bm  = d_in[1];
  const void* Cm  = d_in[2];
  const void* dt  = d_in[3];
  const void* dtb = d_in[4];
  const void* Dv  = d_in[5];
  const int*  ei  = (const int*)d_in[6];
  int Etot = in_sizes[6] / 2;  // 131072

  // allow 128 KiB dynamic LDS for the GEMM (once per process; host-side, capture-safe)
  static int attrDone = 0;
  if (!attrDone){
    hipFuncSetAttribute(reinterpret_cast<const void*>(k_gemm_fused),
                        hipFuncAttributeMaxDynamicSharedMemorySize, 131072);
    attrDone = 1;
  }

  // per-(b,h) chain region: 6 f16 matrices (12 MB):
  //   slots 0-3: L/LT ping-pong pairs, 4,5: O ping/pong
  //   fp32 scatter buffer (4 MB) aliases slots 2+3 (dead before first GEMM writes them)
  const size_t REG = (size_t)6*MSZ*2;  // bytes
  int GB = 1, HB = 1;
  const int cfgs[7][2] = {{8,8},{4,8},{2,8},{1,8},{1,4},{1,2},{1,1}};
  for (int i = 0; i < 7; ++i){
    int gb = cfgs[i][0], hb = cfgs[i][1];
    size_t need = 4ull*(4ull*H_*NTOT + 64)           // coeffs + flag
                + 4ull*(size_t)gb*hb*LG              // nrm
                + 2ull*(size_t)gb*MSZ                // G (f16)
                + (size_t)gb*hb*REG;                 // chain regions
    if (need <= ws_size){ GB = gb; HB = hb; break; }
  }
  int lgHB = (HB==8)?3:((HB==4)?2:((HB==2)?1:0));
  int nbh = GB*HB;

  float* a0  = (float*)d_ws;
  float* a1  = a0 + H_*NTOT;
  float* dum = a1 + H_*NTOT;
  float* sdt = dum + H_*NTOT;
  int*  flag = (int*)(sdt + H_*NTOT);
  float* nrm = (float*)flag + 64;
  f16* G     = (f16*)(nrm + (size_t)nbh*LG);
  char* chainBase = (char*)(G + (size_t)GB*MSZ);

  k_sniff<<<1, 256, 0, stream>>>(dt, flag);
  k_nodecoef<<<(H_*NTOT + 255)/256, 256, 0, stream>>>(dt, dtb, flag, a0, a1, dum, sdt);

  for (int b0 = 0; b0 < BN; b0 += GB){
    for (int h0 = 0; h0 < H_; h0 += HB){
      k_zero<<<dim3(1025, nbh), 256, 0, stream>>>(chainBase, REG, nrm);
      int nthr = GB*EPG*HB;
      k_scatter<<<(nthr + 255)/256, 256, 0, stream>>>(ei, a0, a1, chainBase, REG, nrm,
                                                      b0, h0, lgHB, GB, nthr, Etot);
      k_norm2<<<dim3(32, 32, nbh), 256, 0, stream>>>(chainBase, REG, nrm, dum, b0, h0, HB);
      if (h0 == 0){
        dim3 gg(64, 64, GB);
        k_G<<<gg, 256, 0, stream>>>(Bm, Cm, flag, G, b0);
      }
      // chain schedule: S0; {S_{k+1}, U_k} fused x4; U_4.
      // S: L' = L@L (writes C and C^T).  U: O' = O@L' + O (B-operand = L'^T).
      int lA = 0, lAT = 1, lC = 2, lCT = 3, oA = 4, oC = 5;
      {
        int T = nbh;
        dim3 gg(8, 16, (T + 7)/8);
        k_gemm_fused<<<gg, 1024, 131072, stream>>>(chainBase, REG, nbh, lA, lAT, lC, lCT,
                                                   0, 0, 0, 0);
      }
      for (int k = 0; k < 4; ++k){
        int T = 2*nbh;
        dim3 gg(8, 16, (T + 7)/8);
        k_gemm_fused<<<gg, 1024, 131072, stream>>>(chainBase, REG,
                                                   nbh, lC, lCT, lA, lAT,    // S_{k+1}
                                                   nbh, oA, lCT, oC);        // U_k
        int tp;
        tp = lA; lA = lC; lC = tp;
        tp = lAT; lAT = lCT; lCT = tp;
        tp = oA; oA = oC; oC = tp;
      }
      {
        int T = nbh;
        dim3 gg(8, 16, (T + 7)/8);
        k_gemm_fused<<<gg, 1024, 131072, stream>>>(chainBase, REG, 0, 0, 0, 0, 0,
                                                   nbh, oA, lCT, oC);        // U_4
        int tp = oA; oA = oC; oC = tp;
      }
      dim3 fg(64, nbh);
      k_final2<<<fg, 256, 0, stream>>>(chainBase, REG, oA, G, sdt, x, Dv, flag, d_out, b0, h0, HB);
    }
  }
}